// Round 3
// baseline (467.617 us; speedup 1.0000x reference)
//
#include <hip/hip_runtime.h>
#include <hip/hip_bf16.h>

#define N_NODES 10000
#define N_PAD   10112          // 79 * 128
#define N_EDGES 160000
#define D_H 512
#define BN_EPS 1e-5f
#define LEAKY_SLOPE 0.2f

typedef __attribute__((ext_vector_type(8))) __bf16 bf16x8;
typedef __attribute__((ext_vector_type(4))) float f32x4;

// ---------------- graph preprocessing ----------------

// zero BN stats (5x1024) + cvec (5x512) contiguous [7680 floats]; init counts, deg
__global__ void k_zeroinit(float* fz, int* counts, float* deg) {
    int i = blockIdx.x * 256 + threadIdx.x;
    if (i < 7680) fz[i] = 0.f;
    if (i < N_NODES) { counts[i] = 0; deg[i] = 1.0f; }   // 1.0 = self-loop
}

__global__ void k_count(const int* __restrict__ ei, float* deg, int* counts) {
    int e = blockIdx.x * blockDim.x + threadIdx.x;
    if (e < N_EDGES) {
        int dst = ei[N_EDGES + e];
        atomicAdd(&deg[dst], 1.0f);
        atomicAdd(&counts[dst], 1);
    }
}

// exclusive scan of counts -> rowptr/cursor; also deg -> dinv in place
__global__ __launch_bounds__(1024) void k_scan(const int* __restrict__ counts,
                                               int* rowptr, int* cursor, float* deg) {
    __shared__ int sums[1024];
    int t = threadIdx.x;
    int vals[10];
    int base = t * 10;
    int s = 0;
    #pragma unroll
    for (int j = 0; j < 10; j++) {
        int idx = base + j;
        int v = 0;
        if (idx < N_NODES) { v = counts[idx]; deg[idx] = rsqrtf(deg[idx]); }
        vals[j] = v; s += v;
    }
    sums[t] = s;
    __syncthreads();
    for (int off = 1; off < 1024; off <<= 1) {
        int v = (t >= off) ? sums[t - off] : 0;
        __syncthreads();
        if (t >= off) sums[t] += v;
        __syncthreads();
    }
    int excl = (t == 0) ? 0 : sums[t - 1];
    #pragma unroll
    for (int j = 0; j < 10; j++) {
        int idx = base + j;
        if (idx < N_NODES) { rowptr[idx] = excl; cursor[idx] = excl; excl += vals[j]; }
    }
    if (t == 1023) rowptr[N_NODES] = sums[1023];
}

__global__ void k_fill(const int* __restrict__ ei, int* cursor, int* colidx) {
    int e = blockIdx.x * blockDim.x + threadIdx.x;
    if (e < N_EDGES) {
        int src = ei[e];
        int dst = ei[N_EDGES + e];
        int p = atomicAdd(&cursor[dst], 1);
        colidx[p] = src;
    }
}

// aggw[i] = dinv[i] * (dinv[i] + sum_nbr dinv[s])   (aggregate of all-ones row)
__global__ void k_aggw(const int* __restrict__ rowptr, const int* __restrict__ colidx,
                       const float* __restrict__ dinv, float* __restrict__ aggw) {
    int i = blockIdx.x * 256 + threadIdx.x;
    if (i < N_NODES) {
        float di = dinv[i], s = di;
        int end = rowptr[i + 1];
        for (int e = rowptr[i]; e < end; e++) s += dinv[colidx[e]];
        aggw[i] = di * s;
    }
}

// ---------------- layer-0 weight transpose: W0[256][512] f32 -> Wt0[512][256] bf16 ----

__global__ __launch_bounds__(256) void k_wt(const float* __restrict__ w,
                                            __hip_bfloat16* __restrict__ wt, int di) {
    int r0 = blockIdx.x * 32;             // k dim
    int c0 = blockIdx.y * 32;             // out-col dim
    __shared__ float t[32][33];
    int tx = threadIdx.x & 31, ty = threadIdx.x >> 5;
    for (int rr = ty; rr < 32; rr += 8)
        t[rr][tx] = w[(size_t)(r0 + rr) * 512 + c0 + tx];
    __syncthreads();
    for (int rr = ty; rr < 32; rr += 8)
        wt[(size_t)(c0 + rr) * di + r0 + tx] = __float2bfloat16(t[tx][rr]);
}

// ---------------- BN fold: Wts[col][k] = bf16(sc[k]*W[k][col]); cvec[col] += sh[k]*W[k][col]

__global__ __launch_bounds__(256) void k_fold(const float* __restrict__ W,
        const float* __restrict__ g, const float* __restrict__ beta,
        const float* __restrict__ stats, __hip_bfloat16* __restrict__ Wts,
        float* __restrict__ cvec) {
    __shared__ float t[32][33];
    __shared__ float scs[32], shs[32];
    __shared__ float cpart[8][32];
    int r0 = blockIdx.x * 32;   // k
    int c0 = blockIdx.y * 32;   // col
    int tx = threadIdx.x & 31, ty = threadIdx.x >> 5;
    if (threadIdx.x < 32) {
        int k = r0 + threadIdx.x;
        float mu = stats[k] * (1.f / N_NODES);
        float var = stats[512 + k] * (1.f / N_NODES) - mu * mu;
        float sc = rsqrtf(var + BN_EPS) * g[k];
        scs[threadIdx.x] = sc;
        shs[threadIdx.x] = beta[k] - mu * sc;
    }
    for (int rr = ty; rr < 32; rr += 8)
        t[rr][tx] = W[(size_t)(r0 + rr) * 512 + c0 + tx];
    __syncthreads();
    for (int rr = ty; rr < 32; rr += 8)
        Wts[(size_t)(c0 + rr) * 512 + r0 + tx] = __float2bfloat16(t[tx][rr] * scs[tx]);
    float p = 0.f;
    #pragma unroll
    for (int k = 0; k < 4; ++k) p += shs[ty * 4 + k] * t[ty * 4 + k][tx];
    cpart[ty][tx] = p;
    __syncthreads();
    if (ty == 0) {
        float s = 0.f;
        #pragma unroll
        for (int k2 = 0; k2 < 8; ++k2) s += cpart[k2][tx];
        atomicAdd(&cvec[c0 + tx], s);
    }
}

// ---------------- x convert: f32 [10000][256] -> bf16 ----------------

__global__ __launch_bounds__(256) void k_xcvt(const float* __restrict__ x,
                                              __hip_bfloat16* __restrict__ hb) {
    int i = blockIdx.x * 256 + threadIdx.x;   // 320000 lanes, 8 els each
    size_t base = (size_t)i * 8;
    float4 a = *reinterpret_cast<const float4*>(x + base);
    float4 b = *reinterpret_cast<const float4*>(x + base + 4);
    bf16x8 o;
    o[0] = (__bf16)a.x; o[1] = (__bf16)a.y; o[2] = (__bf16)a.z; o[3] = (__bf16)a.w;
    o[4] = (__bf16)b.x; o[5] = (__bf16)b.y; o[6] = (__bf16)b.z; o[7] = (__bf16)b.w;
    *reinterpret_cast<bf16x8*>((unsigned short*)hb + base) = o;
}

// ---------------- bf16 MFMA GEMM: C[M x 512] = A[Mpad x K] @ Bt[512 x K]^T ----------
// 128x64 tile, 256 threads (4 waves 2x2 -> 64x32 per wave), BK=32, global_load_lds,
// XOR-swizzled LDS (slot ^= (row>>1)&3) via pre-swizzled global source (rule #21),
// bijective XCD swizzle on block id (632 blocks % 8 == 0).

__device__ __forceinline__ void gload16(const void* g, void* l) {
    __builtin_amdgcn_global_load_lds(
        (const __attribute__((address_space(1))) void*)g,
        (__attribute__((address_space(3))) void*)l, 16, 0, 0);
}

template<int OUT_BF16>
__global__ __launch_bounds__(256) void k_gemm_mfma(
        const __hip_bfloat16* __restrict__ A,    // [N_PAD x K] row-major
        const __hip_bfloat16* __restrict__ Bt,   // [512 x K] row-major
        const float* __restrict__ bias1, const float* __restrict__ bias2,
        __hip_bfloat16* __restrict__ Cb, float* __restrict__ Cf,
        int K) {
    __shared__ alignas(16) __hip_bfloat16 As[128][32];
    __shared__ alignas(16) __hip_bfloat16 Bs[64][32];
    // XCD swizzle: 632 blocks, 8 XCDs, q=79 -> each XCD owns ~10 contiguous row panels
    int lin = blockIdx.y * 8 + blockIdx.x;
    int nid = (lin & 7) * 79 + (lin >> 3);
    int row0 = (nid >> 3) * 128;
    int col0 = (nid & 7) * 64;
    int tid = threadIdx.x;
    int lane = tid & 63;
    int w = tid >> 6;
    int wm = w >> 1, wn = w & 1;
    int sr = lane >> 2;                                   // staging row in chunk
    int sk = (((lane & 3) ^ ((lane >> 3) & 3)) << 3);     // pre-swizzled global k offset
    int fl = lane & 15;
    int fso = (((lane >> 4) ^ ((lane >> 1) & 3)) << 3);   // swizzled frag slot offset

    f32x4 acc[4][2] = {};

    for (int k0 = 0; k0 < K; k0 += 32) {
        gload16(A  + (size_t)(row0 + w * 16 + sr) * K + k0 + sk, &As[w * 16][0]);
        gload16(A  + (size_t)(row0 + (w + 4) * 16 + sr) * K + k0 + sk, &As[(w + 4) * 16][0]);
        gload16(Bt + (size_t)(col0 + w * 16 + sr) * K + k0 + sk, &Bs[w * 16][0]);
        __syncthreads();
        bf16x8 af[4], bfr[2];
        #pragma unroll
        for (int i = 0; i < 4; ++i)
            af[i]  = *reinterpret_cast<const bf16x8*>(&As[wm * 64 + i * 16 + fl][fso]);
        #pragma unroll
        for (int j = 0; j < 2; ++j)
            bfr[j] = *reinterpret_cast<const bf16x8*>(&Bs[wn * 32 + j * 16 + fl][fso]);
        #pragma unroll
        for (int i = 0; i < 4; ++i)
            #pragma unroll
            for (int j = 0; j < 2; ++j)
                acc[i][j] = __builtin_amdgcn_mfma_f32_16x16x32_bf16(af[i], bfr[j], acc[i][j], 0, 0, 0);
        __syncthreads();
    }

    int rg = (lane >> 4) * 4;             // C/D: col=lane&15, row=(lane>>4)*4+reg
    #pragma unroll
    for (int i = 0; i < 4; ++i) {
        #pragma unroll
        for (int j = 0; j < 2; ++j) {
            int col = col0 + wn * 32 + j * 16 + fl;
            #pragma unroll
            for (int r = 0; r < 4; ++r) {
                int row = row0 + wm * 64 + i * 16 + rg + r;
                if (row < N_NODES) {
                    float v = acc[i][j][r];
                    if (OUT_BF16) {
                        Cb[(size_t)row * D_H + col] = __float2bfloat16(v);
                    } else {
                        Cf[(size_t)row * D_H + col] = v + bias1[col] + bias2[col];
                    }
                }
            }
        }
    }
}

// ---------------- aggregation + leaky + fused BN stats ----------------
// out[i] = act( dinv[i]*(sum dinv[s]*tmp[s] + dinv[i]*tmp[i]) + b + aggw[i]*c )
// stats[0:512] += sum(out), stats[512:1024] += sum(out^2)

__global__ __launch_bounds__(256) void k_agg(const __hip_bfloat16* __restrict__ tmp,
        const int* __restrict__ rowptr, const int* __restrict__ colidx,
        const float* __restrict__ dinv, const float* __restrict__ bias,
        const float* __restrict__ cvec, const float* __restrict__ aggw,
        __hip_bfloat16* __restrict__ out, float* __restrict__ stats, int relu) {
    __shared__ float reds[4][512];
    __shared__ float redq[4][512];
    int w = threadIdx.x >> 6, lane = threadIdx.x & 63;
    int col0 = lane * 8;
    float sacc[8] = {}, qacc[8] = {};
    #pragma unroll
    for (int nv = 0; nv < 2; ++nv) {
        int node = blockIdx.x * 8 + w * 2 + nv;
        float di = dinv[node];
        bf16x8 v = *reinterpret_cast<const bf16x8*>(tmp + (size_t)node * D_H + col0);
        float s[8];
        #pragma unroll
        for (int j = 0; j < 8; j++) s[j] = di * (float)v[j];
        int beg = rowptr[node], end = rowptr[node + 1];
        int e = beg;
        for (; e + 4 <= end; e += 4) {               // 4-deep MLP batch
            int i0 = colidx[e], i1 = colidx[e + 1], i2 = colidx[e + 2], i3 = colidx[e + 3];
            float d0 = dinv[i0], d1 = dinv[i1], d2 = dinv[i2], d3 = dinv[i3];
            bf16x8 u0 = *reinterpret_cast<const bf16x8*>(tmp + (size_t)i0 * D_H + col0);
            bf16x8 u1 = *reinterpret_cast<const bf16x8*>(tmp + (size_t)i1 * D_H + col0);
            bf16x8 u2 = *reinterpret_cast<const bf16x8*>(tmp + (size_t)i2 * D_H + col0);
            bf16x8 u3 = *reinterpret_cast<const bf16x8*>(tmp + (size_t)i3 * D_H + col0);
            #pragma unroll
            for (int j = 0; j < 8; j++)
                s[j] += d0 * (float)u0[j] + d1 * (float)u1[j] + d2 * (float)u2[j] + d3 * (float)u3[j];
        }
        for (; e < end; ++e) {
            int i0 = colidx[e]; float d0 = dinv[i0];
            bf16x8 u0 = *reinterpret_cast<const bf16x8*>(tmp + (size_t)i0 * D_H + col0);
            #pragma unroll
            for (int j = 0; j < 8; j++) s[j] += d0 * (float)u0[j];
        }
        float aw = cvec ? aggw[node] : 0.f;
        bf16x8 o;
        #pragma unroll
        for (int j = 0; j < 8; j++) {
            float val = di * s[j] + bias[col0 + j];
            if (cvec) val += aw * cvec[col0 + j];
            if (relu) val = (val >= 0.f) ? val : LEAKY_SLOPE * val;
            o[j] = (__bf16)val;
            sacc[j] += val; qacc[j] += val * val;
        }
        *reinterpret_cast<bf16x8*>(out + (size_t)node * D_H + col0) = o;
    }
    #pragma unroll
    for (int j = 0; j < 8; j++) { reds[w][col0 + j] = sacc[j]; redq[w][col0 + j] = qacc[j]; }
    __syncthreads();
    int t = threadIdx.x;
    #pragma unroll
    for (int cc = 0; cc < 2; ++cc) {
        int c = t + cc * 256;
        float ss = reds[0][c] + reds[1][c] + reds[2][c] + reds[3][c];
        float qq = redq[0][c] + redq[1][c] + redq[2][c] + redq[3][c];
        atomicAdd(&stats[c], ss);
        atomicAdd(&stats[512 + c], qq);
    }
}

// ---------------- launch ----------------

extern "C" void kernel_launch(void* const* d_in, const int* in_sizes, int n_in,
                              void* d_out, int out_size, void* d_ws, size_t ws_size,
                              hipStream_t stream) {
    (void)in_sizes; (void)n_in; (void)out_size; (void)ws_size;
    const float* x  = (const float*)d_in[0];
    const int*   ei = (const int*)d_in[1];
    const float *W[6], *bb[5], *gg[5], *beb[5];
    for (int i = 0; i < 5; i++) {
        W[i]   = (const float*)d_in[2 + 4 * i];
        bb[i]  = (const float*)d_in[3 + 4 * i];
        gg[i]  = (const float*)d_in[4 + 4 * i];
        beb[i] = (const float*)d_in[5 + 4 * i];
    }
    W[5] = (const float*)d_in[22];
    const float* bf = (const float*)d_in[23];
    float* out = (float*)d_out;

    // workspace layout (~32.5 MB, 16B-aligned blocks first)
    char* p = (char*)d_ws;
    __hip_bfloat16* hb   = (__hip_bfloat16*)p;  p += (size_t)N_PAD * D_H * 2;     // layer-0 GEMM input
    __hip_bfloat16* hagg = (__hip_bfloat16*)p;  p += (size_t)N_PAD * D_H * 2;     // aggregate output (padded)
    __hip_bfloat16* tmpb = (__hip_bfloat16*)p;  p += (size_t)N_NODES * D_H * 2;   // GEMM output
    __hip_bfloat16* Wt0  = (__hip_bfloat16*)p;  p += (size_t)D_H * 256 * 2;
    __hip_bfloat16* Wts  = (__hip_bfloat16*)p;  p += (size_t)D_H * 512 * 2;       // folded weights (reused)
    float* stats  = (float*)p;  p += 5 * 1024 * 4;   // [5][musum|varsum]
    float* cbuf   = (float*)p;  p += 5 * 512 * 4;    // [5][cvec]  (contiguous with stats for zeroing)
    float* dinv   = (float*)p;  p += N_NODES * 4;
    float* aggw   = (float*)p;  p += N_NODES * 4;
    int* counts   = (int*)p;    p += N_NODES * 4;
    int* rowptr   = (int*)p;    p += (N_NODES + 1) * 4;
    int* cursor   = (int*)p;    p += N_NODES * 4;
    int* colidx   = (int*)p;

    // graph preprocessing
    k_zeroinit<<<40, 256, 0, stream>>>(stats, counts, dinv);
    k_count<<<(N_EDGES + 255) / 256, 256, 0, stream>>>(ei, dinv, counts);
    k_scan<<<1, 1024, 0, stream>>>(counts, rowptr, cursor, dinv);
    k_fill<<<(N_EDGES + 255) / 256, 256, 0, stream>>>(ei, cursor, colidx);
    k_aggw<<<40, 256, 0, stream>>>(rowptr, colidx, dinv, aggw);

    // layer-0 weight transpose + x convert
    k_wt<<<dim3(8, 16), 256, 0, stream>>>(W[0], Wt0, 256);
    k_xcvt<<<1250, 256, 0, stream>>>(x, hb);

    dim3 ggrid(8, N_PAD / 128);   // 632 blocks
    // layer 0
    k_gemm_mfma<1><<<ggrid, 256, 0, stream>>>(hb, Wt0, nullptr, nullptr, tmpb, nullptr, 256);
    k_agg<<<1250, 256, 0, stream>>>(tmpb, rowptr, colidx, dinv, bb[0], nullptr, aggw,
                                    hagg, stats, 1);
    // layers 1..4 (BN of layer l-1 folded into W[l])
    for (int l = 1; l < 5; l++) {
        k_fold<<<dim3(16, 16), 256, 0, stream>>>(W[l], gg[l - 1], beb[l - 1],
                stats + (l - 1) * 1024, Wts, cbuf + (l - 1) * 512);
        k_gemm_mfma<1><<<ggrid, 256, 0, stream>>>(hagg, Wts, nullptr, nullptr, tmpb, nullptr, 512);
        k_agg<<<1250, 256, 0, stream>>>(tmpb, rowptr, colidx, dinv, bb[l],
                cbuf + (l - 1) * 512, aggw, hagg, stats + l * 1024, (l < 4) ? 1 : 0);
    }
    // final: BN(layer4) folded into Wf
    k_fold<<<dim3(16, 16), 256, 0, stream>>>(W[5], gg[4], beb[4],
            stats + 4 * 1024, Wts, cbuf + 4 * 512);
    k_gemm_mfma<0><<<ggrid, 256, 0, stream>>>(hagg, Wts, cbuf + 4 * 512, bf, nullptr, out, 512);
}

// Round 4
// 315.314 us; speedup vs baseline: 1.4830x; 1.4830x over previous
//
#include <hip/hip_runtime.h>
#include <hip/hip_bf16.h>

#define N_NODES 10000
#define N_PAD   10112          // 79 * 128
#define N_EDGES 160000
#define D_H 512
#define BN_EPS 1e-5f
#define LEAKY_SLOPE 0.2f

typedef __attribute__((ext_vector_type(8))) __bf16 bf16x8;
typedef __attribute__((ext_vector_type(4))) float f32x4;

// ---------------- init: zero stats(5x8x1024)+cvec(5x512)=43520 f, counts, deg, zero-row ----

__global__ void k_zeroinit(float* fz, int* counts, float* deg, __hip_bfloat16* tmpz) {
    int i = blockIdx.x * 256 + threadIdx.x;
    if (i < 43520) fz[i] = 0.f;
    if (i < N_NODES) { counts[i] = 0; deg[i] = 1.0f; }   // 1.0 = self-loop
    else if (i == N_NODES) deg[i] = 0.f;                 // dummy node -> dinv 0
    if (i < 256) ((unsigned int*)tmpz)[i] = 0u;          // zero row (512 bf16)
}

__global__ void k_count(const int* __restrict__ ei, float* deg, int* counts) {
    int e = blockIdx.x * blockDim.x + threadIdx.x;
    if (e < N_EDGES) {
        int dst = ei[N_EDGES + e];
        atomicAdd(&deg[dst], 1.0f);
        atomicAdd(&counts[dst], 1);
    }
}

// exclusive scan of padded counts -> rowptr/cursor; deg -> dinv in place
__global__ __launch_bounds__(1024) void k_scan(const int* __restrict__ counts,
                                               int* rowptr, int* cursor, float* deg) {
    __shared__ int sums[1024];
    int t = threadIdx.x;
    int vals[10];
    int base = t * 10;
    int s = 0;
    #pragma unroll
    for (int j = 0; j < 10; j++) {
        int idx = base + j;
        int v = 0;
        if (idx < N_NODES) {
            v = (counts[idx] + 3) & ~3;                  // pad to multiple of 4
            deg[idx] = rsqrtf(deg[idx]);
        }
        vals[j] = v; s += v;
    }
    sums[t] = s;
    __syncthreads();
    for (int off = 1; off < 1024; off <<= 1) {
        int v = (t >= off) ? sums[t - off] : 0;
        __syncthreads();
        if (t >= off) sums[t] += v;
        __syncthreads();
    }
    int excl = (t == 0) ? 0 : sums[t - 1];
    #pragma unroll
    for (int j = 0; j < 10; j++) {
        int idx = base + j;
        if (idx < N_NODES) { rowptr[idx] = excl; cursor[idx] = excl; excl += vals[j]; }
    }
    if (t == 1023) rowptr[N_NODES] = sums[1023];
}

__global__ void k_fill(const int* __restrict__ ei, int* cursor, int* colidx) {
    int e = blockIdx.x * blockDim.x + threadIdx.x;
    if (e < N_EDGES) {
        int src = ei[e];
        int dst = ei[N_EDGES + e];
        int p = atomicAdd(&cursor[dst], 1);
        colidx[p] = src;
    }
}

// fill padding slots with dummy node (points at zero row)
__global__ void k_pad(const int* __restrict__ rowptr, const int* __restrict__ cursor,
                      int* colidx) {
    int i = blockIdx.x * 256 + threadIdx.x;
    if (i < N_NODES) {
        int end = rowptr[i + 1];
        for (int e = cursor[i]; e < end; e++) colidx[e] = N_NODES;
    }
}

// aggw[i] = dinv[i] * (dinv[i] + sum_nbr dinv[s])   (dinv[dummy]=0 so pads are no-ops)
__global__ void k_aggw(const int* __restrict__ rowptr, const int* __restrict__ colidx,
                       const float* __restrict__ dinv, float* __restrict__ aggw) {
    int i = blockIdx.x * 256 + threadIdx.x;
    if (i < N_NODES) {
        float di = dinv[i], s = di;
        int end = rowptr[i + 1];
        for (int e = rowptr[i]; e < end; e++) s += dinv[colidx[e]];
        aggw[i] = di * s;
    }
}

// ---------------- layer-0 weight transpose: W0[256][512] f32 -> Wt0[512][256] bf16 ----

__global__ __launch_bounds__(256) void k_wt(const float* __restrict__ w,
                                            __hip_bfloat16* __restrict__ wt, int di) {
    int r0 = blockIdx.x * 32;
    int c0 = blockIdx.y * 32;
    __shared__ float t[32][33];
    int tx = threadIdx.x & 31, ty = threadIdx.x >> 5;
    for (int rr = ty; rr < 32; rr += 8)
        t[rr][tx] = w[(size_t)(r0 + rr) * 512 + c0 + tx];
    __syncthreads();
    for (int rr = ty; rr < 32; rr += 8)
        wt[(size_t)(c0 + rr) * di + r0 + tx] = __float2bfloat16(t[tx][rr]);
}

// ---------------- BN fold: Wts[col][k] = bf16(sc[k]*W[k][col]); cvec[col] += sh[k]*W[k][col]
// stats layout: 8 buckets x [sum(512) | sumsq(512)]

__global__ __launch_bounds__(256) void k_fold(const float* __restrict__ W,
        const float* __restrict__ g, const float* __restrict__ beta,
        const float* __restrict__ stats, __hip_bfloat16* __restrict__ Wts,
        float* __restrict__ cvec) {
    __shared__ float t[32][33];
    __shared__ float scs[32], shs[32];
    __shared__ float cpart[8][32];
    int r0 = blockIdx.x * 32;   // k
    int c0 = blockIdx.y * 32;   // col
    int tx = threadIdx.x & 31, ty = threadIdx.x >> 5;
    if (threadIdx.x < 32) {
        int k = r0 + threadIdx.x;
        float ssum = 0.f, qsum = 0.f;
        #pragma unroll
        for (int b = 0; b < 8; b++) {
            ssum += stats[b * 1024 + k];
            qsum += stats[b * 1024 + 512 + k];
        }
        float mu = ssum * (1.f / N_NODES);
        float var = qsum * (1.f / N_NODES) - mu * mu;
        float sc = rsqrtf(var + BN_EPS) * g[k];
        scs[threadIdx.x] = sc;
        shs[threadIdx.x] = beta[k] - mu * sc;
    }
    for (int rr = ty; rr < 32; rr += 8)
        t[rr][tx] = W[(size_t)(r0 + rr) * 512 + c0 + tx];
    __syncthreads();
    for (int rr = ty; rr < 32; rr += 8)
        Wts[(size_t)(c0 + rr) * 512 + r0 + tx] = __float2bfloat16(t[tx][rr] * scs[tx]);
    float p = 0.f;
    #pragma unroll
    for (int k = 0; k < 4; ++k) p += shs[ty * 4 + k] * t[ty * 4 + k][tx];
    cpart[ty][tx] = p;
    __syncthreads();
    if (ty == 0) {
        float s = 0.f;
        #pragma unroll
        for (int k2 = 0; k2 < 8; ++k2) s += cpart[k2][tx];
        atomicAdd(&cvec[c0 + tx], s);
    }
}

// ---------------- x convert ----------------

__global__ __launch_bounds__(256) void k_xcvt(const float* __restrict__ x,
                                              __hip_bfloat16* __restrict__ hb) {
    int i = blockIdx.x * 256 + threadIdx.x;
    size_t base = (size_t)i * 8;
    float4 a = *reinterpret_cast<const float4*>(x + base);
    float4 b = *reinterpret_cast<const float4*>(x + base + 4);
    bf16x8 o;
    o[0] = (__bf16)a.x; o[1] = (__bf16)a.y; o[2] = (__bf16)a.z; o[3] = (__bf16)a.w;
    o[4] = (__bf16)b.x; o[5] = (__bf16)b.y; o[6] = (__bf16)b.z; o[7] = (__bf16)b.w;
    *reinterpret_cast<bf16x8*>((unsigned short*)hb + base) = o;
}

// ---------------- bf16 MFMA GEMM (128x64 tile, prescale-by-dinv epilogue) ----------

__device__ __forceinline__ void gload16(const void* g, void* l) {
    __builtin_amdgcn_global_load_lds(
        (const __attribute__((address_space(1))) void*)g,
        (__attribute__((address_space(3))) void*)l, 16, 0, 0);
}

template<int OUT_BF16>
__global__ __launch_bounds__(256) void k_gemm_mfma(
        const __hip_bfloat16* __restrict__ A,    // [N_PAD x K] row-major
        const __hip_bfloat16* __restrict__ Bt,   // [512 x K] row-major
        const float* __restrict__ dinv,
        const float* __restrict__ bias1, const float* __restrict__ bias2,
        __hip_bfloat16* __restrict__ Cb, float* __restrict__ Cf,
        int K) {
    __shared__ alignas(16) __hip_bfloat16 As[128][32];
    __shared__ alignas(16) __hip_bfloat16 Bs[64][32];
    int lin = blockIdx.y * 8 + blockIdx.x;
    int nid = (lin & 7) * 79 + (lin >> 3);       // bijective XCD swizzle (632 = 8*79)
    int row0 = (nid >> 3) * 128;
    int col0 = (nid & 7) * 64;
    int tid = threadIdx.x;
    int lane = tid & 63;
    int w = tid >> 6;
    int wm = w >> 1, wn = w & 1;
    int sr = lane >> 2;
    int sk = (((lane & 3) ^ ((lane >> 3) & 3)) << 3);     // pre-swizzled global k offset
    int fl = lane & 15;
    int fso = (((lane >> 4) ^ ((lane >> 1) & 3)) << 3);   // swizzled frag slot offset

    f32x4 acc[4][2] = {};

    for (int k0 = 0; k0 < K; k0 += 32) {
        gload16(A  + (size_t)(row0 + w * 16 + sr) * K + k0 + sk, &As[w * 16][0]);
        gload16(A  + (size_t)(row0 + (w + 4) * 16 + sr) * K + k0 + sk, &As[(w + 4) * 16][0]);
        gload16(Bt + (size_t)(col0 + w * 16 + sr) * K + k0 + sk, &Bs[w * 16][0]);
        __syncthreads();
        bf16x8 af[4], bfr[2];
        #pragma unroll
        for (int i = 0; i < 4; ++i)
            af[i]  = *reinterpret_cast<const bf16x8*>(&As[wm * 64 + i * 16 + fl][fso]);
        #pragma unroll
        for (int j = 0; j < 2; ++j)
            bfr[j] = *reinterpret_cast<const bf16x8*>(&Bs[wn * 32 + j * 16 + fl][fso]);
        #pragma unroll
        for (int i = 0; i < 4; ++i)
            #pragma unroll
            for (int j = 0; j < 2; ++j)
                acc[i][j] = __builtin_amdgcn_mfma_f32_16x16x32_bf16(af[i], bfr[j], acc[i][j], 0, 0, 0);
        __syncthreads();
    }

    int rg = (lane >> 4) * 4;             // C/D: col=lane&15, row=(lane>>4)*4+reg
    #pragma unroll
    for (int i = 0; i < 4; ++i) {
        #pragma unroll
        for (int r = 0; r < 4; ++r) {
            int row = row0 + wm * 64 + i * 16 + rg + r;
            if (row < N_NODES) {
                if (OUT_BF16) {
                    float sc = dinv[row];
                    #pragma unroll
                    for (int j = 0; j < 2; ++j) {
                        int col = col0 + wn * 32 + j * 16 + fl;
                        Cb[(size_t)row * D_H + col] = __float2bfloat16(acc[i][j][r] * sc);
                    }
                } else {
                    #pragma unroll
                    for (int j = 0; j < 2; ++j) {
                        int col = col0 + wn * 32 + j * 16 + fl;
                        Cf[(size_t)row * D_H + col] = acc[i][j][r] + bias1[col] + bias2[col];
                    }
                }
            }
        }
    }
}

// ---------------- aggregation + leaky + fused BN stats ----------------
// rows of tmp are PRE-SCALED by dinv[src]; pads hit the all-zero row.
// out[i] = act( dinv[i]*(tmp'[i] + sum_e tmp'[src]) + b + aggw[i]*c )

template<int RELU, int HASC>
__global__ __launch_bounds__(256) void k_agg(const __hip_bfloat16* __restrict__ tmp,
        const int* __restrict__ rowptr, const int* __restrict__ colidx,
        const float* __restrict__ dinv, const float* __restrict__ bias,
        const float* __restrict__ cvec, const float* __restrict__ aggw,
        __hip_bfloat16* __restrict__ out, float* __restrict__ stats) {
    __shared__ float reds[4][512];
    __shared__ float redq[4][512];
    int w = threadIdx.x >> 6, lane = threadIdx.x & 63;
    int col0 = lane * 8;
    int node = blockIdx.x * 4 + w;
    float di = dinv[node];
    bf16x8 v = *reinterpret_cast<const bf16x8*>(tmp + (size_t)node * D_H + col0);
    float s[8];
    #pragma unroll
    for (int j = 0; j < 8; j++) s[j] = (float)v[j];
    int beg = rowptr[node], end = rowptr[node + 1];
    for (int e = beg; e < end; e += 4) {
        int4 iv = *reinterpret_cast<const int4*>(colidx + e);   // beg % 4 == 0
        bf16x8 u0 = *reinterpret_cast<const bf16x8*>(tmp + (size_t)iv.x * D_H + col0);
        bf16x8 u1 = *reinterpret_cast<const bf16x8*>(tmp + (size_t)iv.y * D_H + col0);
        bf16x8 u2 = *reinterpret_cast<const bf16x8*>(tmp + (size_t)iv.z * D_H + col0);
        bf16x8 u3 = *reinterpret_cast<const bf16x8*>(tmp + (size_t)iv.w * D_H + col0);
        #pragma unroll
        for (int j = 0; j < 8; j++)
            s[j] += ((float)u0[j] + (float)u1[j]) + ((float)u2[j] + (float)u3[j]);
    }
    float aw = HASC ? aggw[node] : 0.f;
    bf16x8 o;
    float sacc[8], qacc[8];
    #pragma unroll
    for (int j = 0; j < 8; j++) {
        float val = di * s[j] + bias[col0 + j];
        if (HASC) val += aw * cvec[col0 + j];
        if (RELU) val = (val >= 0.f) ? val : LEAKY_SLOPE * val;
        o[j] = (__bf16)val;
        sacc[j] = val; qacc[j] = val * val;
    }
    *reinterpret_cast<bf16x8*>(out + (size_t)node * D_H + col0) = o;
    #pragma unroll
    for (int j = 0; j < 8; j++) { reds[w][col0 + j] = sacc[j]; redq[w][col0 + j] = qacc[j]; }
    __syncthreads();
    float* sb = stats + (blockIdx.x & 7) * 1024;
    #pragma unroll
    for (int cc = 0; cc < 2; ++cc) {
        int c = threadIdx.x + cc * 256;
        float ss = reds[0][c] + reds[1][c] + reds[2][c] + reds[3][c];
        float qq = redq[0][c] + redq[1][c] + redq[2][c] + redq[3][c];
        atomicAdd(&sb[c], ss);
        atomicAdd(&sb[512 + c], qq);
    }
}

// ---------------- launch ----------------

extern "C" void kernel_launch(void* const* d_in, const int* in_sizes, int n_in,
                              void* d_out, int out_size, void* d_ws, size_t ws_size,
                              hipStream_t stream) {
    (void)in_sizes; (void)n_in; (void)out_size; (void)ws_size;
    const float* x  = (const float*)d_in[0];
    const int*   ei = (const int*)d_in[1];
    const float *W[6], *bb[5], *gg[5], *beb[5];
    for (int i = 0; i < 5; i++) {
        W[i]   = (const float*)d_in[2 + 4 * i];
        bb[i]  = (const float*)d_in[3 + 4 * i];
        gg[i]  = (const float*)d_in[4 + 4 * i];
        beb[i] = (const float*)d_in[5 + 4 * i];
    }
    W[5] = (const float*)d_in[22];
    const float* bf = (const float*)d_in[23];
    float* out = (float*)d_out;

    // workspace layout
    char* p = (char*)d_ws;
    __hip_bfloat16* hb   = (__hip_bfloat16*)p;  p += (size_t)N_PAD * D_H * 2;
    __hip_bfloat16* hagg = (__hip_bfloat16*)p;  p += (size_t)N_PAD * D_H * 2;
    __hip_bfloat16* tmpb = (__hip_bfloat16*)p;  p += (size_t)N_PAD * D_H * 2;   // row 10000 = zero row
    __hip_bfloat16* Wt0  = (__hip_bfloat16*)p;  p += (size_t)D_H * 256 * 2;
    __hip_bfloat16* Wts  = (__hip_bfloat16*)p;  p += (size_t)D_H * 512 * 2;
    float* stats  = (float*)p;  p += 5 * 8192 * 4;   // [5][8 buckets][1024]
    float* cbuf   = (float*)p;  p += 5 * 512 * 4;    // contiguous with stats for zeroing
    float* dinv   = (float*)p;  p += (N_NODES + 1) * 4;
    float* aggw   = (float*)p;  p += N_NODES * 4;
    int* counts   = (int*)p;    p += N_NODES * 4;
    int* rowptr   = (int*)p;    p += (N_NODES + 1) * 4;
    int* cursor   = (int*)p;    p += N_NODES * 4;
    int* colidx   = (int*)p;                         // <= 200000 ints

    // preprocessing
    k_zeroinit<<<170, 256, 0, stream>>>(stats, counts, dinv, tmpb + (size_t)N_NODES * D_H);
    k_count<<<(N_EDGES + 255) / 256, 256, 0, stream>>>(ei, dinv, counts);
    k_scan<<<1, 1024, 0, stream>>>(counts, rowptr, cursor, dinv);
    k_fill<<<(N_EDGES + 255) / 256, 256, 0, stream>>>(ei, cursor, colidx);
    k_pad<<<40, 256, 0, stream>>>(rowptr, cursor, colidx);
    k_aggw<<<40, 256, 0, stream>>>(rowptr, colidx, dinv, aggw);
    k_wt<<<dim3(8, 16), 256, 0, stream>>>(W[0], Wt0, 256);
    k_xcvt<<<1250, 256, 0, stream>>>(x, hb);

    dim3 ggrid(8, N_PAD / 128);   // 632 blocks
    // layer 0
    k_gemm_mfma<1><<<ggrid, 256, 0, stream>>>(hb, Wt0, dinv, nullptr, nullptr, tmpb, nullptr, 256);
    k_agg<1, 0><<<2500, 256, 0, stream>>>(tmpb, rowptr, colidx, dinv, bb[0], nullptr, aggw,
                                          hagg, stats);
    // layers 1..4 (BN of layer l-1 folded into W[l])
    for (int l = 1; l < 5; l++) {
        k_fold<<<dim3(16, 16), 256, 0, stream>>>(W[l], gg[l - 1], beb[l - 1],
                stats + (l - 1) * 8192, Wts, cbuf + (l - 1) * 512);
        k_gemm_mfma<1><<<ggrid, 256, 0, stream>>>(hagg, Wts, dinv, nullptr, nullptr, tmpb, nullptr, 512);
        if (l < 4)
            k_agg<1, 1><<<2500, 256, 0, stream>>>(tmpb, rowptr, colidx, dinv, bb[l],
                    cbuf + (l - 1) * 512, aggw, hagg, stats + l * 8192);
        else
            k_agg<0, 1><<<2500, 256, 0, stream>>>(tmpb, rowptr, colidx, dinv, bb[l],
                    cbuf + (l - 1) * 512, aggw, hagg, stats + l * 8192);
    }
    // final: BN(layer4) folded into Wf
    k_fold<<<dim3(16, 16), 256, 0, stream>>>(W[5], gg[4], beb[4],
            stats + 4 * 8192, Wts, cbuf + 4 * 512);
    k_gemm_mfma<0><<<ggrid, 256, 0, stream>>>(hagg, Wts, dinv, cbuf + 4 * 512, bf, nullptr, out, 512);
}

// Round 5
// 311.167 us; speedup vs baseline: 1.5028x; 1.0133x over previous
//
#include <hip/hip_runtime.h>
#include <hip/hip_bf16.h>

#define N_NODES 10000
#define N_PAD   10112          // 79 * 128
#define N_EDGES 160000
#define D_H 512
#define BN_EPS 1e-5f
#define LEAKY_SLOPE 0.2f

typedef __attribute__((ext_vector_type(8))) __bf16 bf16x8;
typedef __attribute__((ext_vector_type(4))) float f32x4;

// ---------------- init: zero stats(5x8x1024)+cvec(5x512)=43520 f, counts, deg, zero-row ----

__global__ void k_zeroinit(float* fz, int* counts, float* deg, __hip_bfloat16* tmpz) {
    int i = blockIdx.x * 256 + threadIdx.x;
    if (i < 43520) fz[i] = 0.f;
    if (i < N_NODES) { counts[i] = 0; deg[i] = 1.0f; }   // 1.0 = self-loop
    else if (i == N_NODES) deg[i] = 0.f;                 // dummy node -> dinv 0
    if (i < 256) ((unsigned int*)tmpz)[i] = 0u;          // zero row (512 bf16)
}

__global__ void k_count(const int* __restrict__ ei, float* deg, int* counts) {
    int e = blockIdx.x * blockDim.x + threadIdx.x;
    if (e < N_EDGES) {
        int dst = ei[N_EDGES + e];
        atomicAdd(&deg[dst], 1.0f);
        atomicAdd(&counts[dst], 1);
    }
}

// exclusive scan of counts padded to multiple of 8 -> rowptr/cursor; deg -> dinv in place
__global__ __launch_bounds__(1024) void k_scan(const int* __restrict__ counts,
                                               int* rowptr, int* cursor, float* deg) {
    __shared__ int sums[1024];
    int t = threadIdx.x;
    int vals[10];
    int base = t * 10;
    int s = 0;
    #pragma unroll
    for (int j = 0; j < 10; j++) {
        int idx = base + j;
        int v = 0;
        if (idx < N_NODES) {
            v = (counts[idx] + 7) & ~7;                  // pad to multiple of 8
            deg[idx] = rsqrtf(deg[idx]);
        }
        vals[j] = v; s += v;
    }
    sums[t] = s;
    __syncthreads();
    for (int off = 1; off < 1024; off <<= 1) {
        int v = (t >= off) ? sums[t - off] : 0;
        __syncthreads();
        if (t >= off) sums[t] += v;
        __syncthreads();
    }
    int excl = (t == 0) ? 0 : sums[t - 1];
    #pragma unroll
    for (int j = 0; j < 10; j++) {
        int idx = base + j;
        if (idx < N_NODES) { rowptr[idx] = excl; cursor[idx] = excl; excl += vals[j]; }
    }
    if (t == 1023) rowptr[N_NODES] = sums[1023];
}

__global__ void k_fill(const int* __restrict__ ei, int* cursor, int* colidx) {
    int e = blockIdx.x * blockDim.x + threadIdx.x;
    if (e < N_EDGES) {
        int src = ei[e];
        int dst = ei[N_EDGES + e];
        int p = atomicAdd(&cursor[dst], 1);
        colidx[p] = src;
    }
}

// merged: fill padding slots with dummy node + compute aggw over real edges
__global__ void k_pa(const int* __restrict__ rowptr, const int* __restrict__ cursor,
                     int* colidx, const float* __restrict__ dinv, float* __restrict__ aggw) {
    int i = blockIdx.x * 256 + threadIdx.x;
    if (i < N_NODES) {
        int beg = rowptr[i], real_end = cursor[i], end = rowptr[i + 1];
        for (int e = real_end; e < end; e++) colidx[e] = N_NODES;
        float di = dinv[i], s = di;
        for (int e = beg; e < real_end; e++) s += dinv[colidx[e]];
        aggw[i] = di * s;
    }
}

// ---------------- layer-0 weight transpose: W0[256][512] f32 -> Wt0[512][256] bf16 ----

__global__ __launch_bounds__(256) void k_wt(const float* __restrict__ w,
                                            __hip_bfloat16* __restrict__ wt, int di) {
    int r0 = blockIdx.x * 32;
    int c0 = blockIdx.y * 32;
    __shared__ float t[32][33];
    int tx = threadIdx.x & 31, ty = threadIdx.x >> 5;
    for (int rr = ty; rr < 32; rr += 8)
        t[rr][tx] = w[(size_t)(r0 + rr) * 512 + c0 + tx];
    __syncthreads();
    for (int rr = ty; rr < 32; rr += 8)
        wt[(size_t)(c0 + rr) * di + r0 + tx] = __float2bfloat16(t[tx][rr]);
}

// ---------------- BN fold: Wts[col][k] = bf16(sc[k]*W[k][col]); cvec[col] += sh[k]*W[k][col]
// stats layout: 8 buckets x [sum(512) | sumsq(512)]

__global__ __launch_bounds__(256) void k_fold(const float* __restrict__ W,
        const float* __restrict__ g, const float* __restrict__ beta,
        const float* __restrict__ stats, __hip_bfloat16* __restrict__ Wts,
        float* __restrict__ cvec) {
    __shared__ float t[32][33];
    __shared__ float scs[32], shs[32];
    __shared__ float cpart[8][32];
    int r0 = blockIdx.x * 32;   // k
    int c0 = blockIdx.y * 32;   // col
    int tx = threadIdx.x & 31, ty = threadIdx.x >> 5;
    if (threadIdx.x < 32) {
        int k = r0 + threadIdx.x;
        float ssum = 0.f, qsum = 0.f;
        #pragma unroll
        for (int b = 0; b < 8; b++) {
            ssum += stats[b * 1024 + k];
            qsum += stats[b * 1024 + 512 + k];
        }
        float mu = ssum * (1.f / N_NODES);
        float var = qsum * (1.f / N_NODES) - mu * mu;
        float sc = rsqrtf(var + BN_EPS) * g[k];
        scs[threadIdx.x] = sc;
        shs[threadIdx.x] = beta[k] - mu * sc;
    }
    for (int rr = ty; rr < 32; rr += 8)
        t[rr][tx] = W[(size_t)(r0 + rr) * 512 + c0 + tx];
    __syncthreads();
    for (int rr = ty; rr < 32; rr += 8)
        Wts[(size_t)(c0 + rr) * 512 + r0 + tx] = __float2bfloat16(t[tx][rr] * scs[tx]);
    float p = 0.f;
    #pragma unroll
    for (int k = 0; k < 4; ++k) p += shs[ty * 4 + k] * t[ty * 4 + k][tx];
    cpart[ty][tx] = p;
    __syncthreads();
    if (ty == 0) {
        float s = 0.f;
        #pragma unroll
        for (int k2 = 0; k2 < 8; ++k2) s += cpart[k2][tx];
        atomicAdd(&cvec[c0 + tx], s);
    }
}

// ---------------- x convert ----------------

__global__ __launch_bounds__(256) void k_xcvt(const float* __restrict__ x,
                                              __hip_bfloat16* __restrict__ hb) {
    int i = blockIdx.x * 256 + threadIdx.x;
    size_t base = (size_t)i * 8;
    float4 a = *reinterpret_cast<const float4*>(x + base);
    float4 b = *reinterpret_cast<const float4*>(x + base + 4);
    bf16x8 o;
    o[0] = (__bf16)a.x; o[1] = (__bf16)a.y; o[2] = (__bf16)a.z; o[3] = (__bf16)a.w;
    o[4] = (__bf16)b.x; o[5] = (__bf16)b.y; o[6] = (__bf16)b.z; o[7] = (__bf16)b.w;
    *reinterpret_cast<bf16x8*>((unsigned short*)hb + base) = o;
}

// ---------------- bf16 MFMA GEMM (128x64 tile, 2-phase double-buffered, K templated) ----

__device__ __forceinline__ void gload16(const void* g, void* l) {
    __builtin_amdgcn_global_load_lds(
        (const __attribute__((address_space(1))) void*)g,
        (__attribute__((address_space(3))) void*)l, 16, 0, 0);
}

template<int OUT_BF16, int K>
__global__ __launch_bounds__(256) void k_gemm_mfma(
        const __hip_bfloat16* __restrict__ A,    // [N_PAD x K] row-major
        const __hip_bfloat16* __restrict__ Bt,   // [512 x K] row-major
        const float* __restrict__ dinv,
        const float* __restrict__ bias1, const float* __restrict__ bias2,
        __hip_bfloat16* __restrict__ Cb, float* __restrict__ Cf) {
    __shared__ alignas(16) __hip_bfloat16 As[2][128][32];
    __shared__ alignas(16) __hip_bfloat16 Bs[2][64][32];
    int lin = blockIdx.y * 8 + blockIdx.x;
    int nid = (lin & 7) * 79 + (lin >> 3);       // bijective XCD swizzle (632 = 8*79)
    int row0 = (nid >> 3) * 128;
    int col0 = (nid & 7) * 64;
    int tid = threadIdx.x;
    int lane = tid & 63;
    int w = tid >> 6;
    int wm = w >> 1, wn = w & 1;
    int sr = lane >> 2;
    int sk = (((lane & 3) ^ ((lane >> 3) & 3)) << 3);     // pre-swizzled global k offset
    int fl = lane & 15;
    int fso = (((lane >> 4) ^ ((lane >> 1) & 3)) << 3);   // swizzled frag slot offset

    const __hip_bfloat16* ga = A  + (size_t)(row0 + w * 16 + sr) * K + sk;
    const __hip_bfloat16* gb = Bt + (size_t)(col0 + w * 16 + sr) * K + sk;

    f32x4 acc[4][2] = {};
    constexpr int NSTEP = K / 32;

    // prologue: stage tile 0
    gload16(ga, &As[0][w * 16][0]);
    gload16(ga + (size_t)64 * K, &As[0][(w + 4) * 16][0]);
    gload16(gb, &Bs[0][w * 16][0]);
    __syncthreads();

    #pragma unroll
    for (int t = 0; t < NSTEP; ++t) {
        int cur = t & 1;
        if (t + 1 < NSTEP) {            // stage next tile BEFORE compute (T3 2-phase)
            int k0 = (t + 1) * 32;
            gload16(ga + k0, &As[cur ^ 1][w * 16][0]);
            gload16(ga + (size_t)64 * K + k0, &As[cur ^ 1][(w + 4) * 16][0]);
            gload16(gb + k0, &Bs[cur ^ 1][w * 16][0]);
        }
        bf16x8 af[4], bfr[2];
        #pragma unroll
        for (int i = 0; i < 4; ++i)
            af[i]  = *reinterpret_cast<const bf16x8*>(&As[cur][wm * 64 + i * 16 + fl][fso]);
        #pragma unroll
        for (int j = 0; j < 2; ++j)
            bfr[j] = *reinterpret_cast<const bf16x8*>(&Bs[cur][wn * 32 + j * 16 + fl][fso]);
        #pragma unroll
        for (int i = 0; i < 4; ++i)
            #pragma unroll
            for (int j = 0; j < 2; ++j)
                acc[i][j] = __builtin_amdgcn_mfma_f32_16x16x32_bf16(af[i], bfr[j], acc[i][j], 0, 0, 0);
        __syncthreads();                // one barrier per K-step (drains vm+lgkm)
    }

    int rg = (lane >> 4) * 4;             // C/D: col=lane&15, row=(lane>>4)*4+reg
    #pragma unroll
    for (int i = 0; i < 4; ++i) {
        #pragma unroll
        for (int r = 0; r < 4; ++r) {
            int row = row0 + wm * 64 + i * 16 + rg + r;
            if (row < N_NODES) {
                if (OUT_BF16) {
                    float sc = dinv[row];
                    #pragma unroll
                    for (int j = 0; j < 2; ++j) {
                        int col = col0 + wn * 32 + j * 16 + fl;
                        Cb[(size_t)row * D_H + col] = __float2bfloat16(acc[i][j][r] * sc);
                    }
                } else {
                    #pragma unroll
                    for (int j = 0; j < 2; ++j) {
                        int col = col0 + wn * 32 + j * 16 + fl;
                        Cf[(size_t)row * D_H + col] = acc[i][j][r] + bias1[col] + bias2[col];
                    }
                }
            }
        }
    }
}

// ---------------- aggregation + leaky + fused BN stats ----------------
// rows of tmp are PRE-SCALED by dinv[src]; CSR padded to 8, pads hit the zero row.
// out[i] = act( dinv[i]*(tmp'[i] + sum_e tmp'[src]) + b + aggw[i]*c )

template<int RELU, int HASC>
__global__ __launch_bounds__(256) void k_agg(const __hip_bfloat16* __restrict__ tmp,
        const int* __restrict__ rowptr, const int* __restrict__ colidx,
        const float* __restrict__ dinv, const float* __restrict__ bias,
        const float* __restrict__ cvec, const float* __restrict__ aggw,
        __hip_bfloat16* __restrict__ out, float* __restrict__ stats) {
    __shared__ float reds[4][512];
    __shared__ float redq[4][512];
    int w = threadIdx.x >> 6, lane = threadIdx.x & 63;
    int col0 = lane * 8;
    int node = blockIdx.x * 4 + w;
    const __hip_bfloat16* base = tmp + col0;
    float di = dinv[node];
    bf16x8 v = *reinterpret_cast<const bf16x8*>(base + (size_t)node * D_H);
    float s[8];
    #pragma unroll
    for (int j = 0; j < 8; j++) s[j] = (float)v[j];
    int beg = rowptr[node], end = rowptr[node + 1];
    if (beg < end) {
        int4 iv0 = *reinterpret_cast<const int4*>(colidx + beg);
        int4 iv1 = *reinterpret_cast<const int4*>(colidx + beg + 4);
        for (int e = beg; e < end; e += 8) {
            int4 nv0 = iv0, nv1 = iv1;
            int en = e + 8;
            if (en < end) {             // prefetch next indices before consuming rows
                nv0 = *reinterpret_cast<const int4*>(colidx + en);
                nv1 = *reinterpret_cast<const int4*>(colidx + en + 4);
            }
            bf16x8 u0 = *reinterpret_cast<const bf16x8*>(base + (size_t)iv0.x * D_H);
            bf16x8 u1 = *reinterpret_cast<const bf16x8*>(base + (size_t)iv0.y * D_H);
            bf16x8 u2 = *reinterpret_cast<const bf16x8*>(base + (size_t)iv0.z * D_H);
            bf16x8 u3 = *reinterpret_cast<const bf16x8*>(base + (size_t)iv0.w * D_H);
            bf16x8 u4 = *reinterpret_cast<const bf16x8*>(base + (size_t)iv1.x * D_H);
            bf16x8 u5 = *reinterpret_cast<const bf16x8*>(base + (size_t)iv1.y * D_H);
            bf16x8 u6 = *reinterpret_cast<const bf16x8*>(base + (size_t)iv1.z * D_H);
            bf16x8 u7 = *reinterpret_cast<const bf16x8*>(base + (size_t)iv1.w * D_H);
            #pragma unroll
            for (int j = 0; j < 8; j++)
                s[j] += (((float)u0[j] + (float)u1[j]) + ((float)u2[j] + (float)u3[j]))
                      + (((float)u4[j] + (float)u5[j]) + ((float)u6[j] + (float)u7[j]));
            iv0 = nv0; iv1 = nv1;
        }
    }
    float aw = HASC ? aggw[node] : 0.f;
    bf16x8 o;
    #pragma unroll
    for (int j = 0; j < 8; j++) {
        float val = di * s[j] + bias[col0 + j];
        if (HASC) val += aw * cvec[col0 + j];
        if (RELU) val = (val >= 0.f) ? val : LEAKY_SLOPE * val;
        o[j] = (__bf16)val;
        reds[w][col0 + j] = val;
        redq[w][col0 + j] = val * val;
    }
    *reinterpret_cast<bf16x8*>(out + (size_t)node * D_H + col0) = o;
    __syncthreads();
    float* sb = stats + (blockIdx.x & 7) * 1024;
    #pragma unroll
    for (int cc = 0; cc < 2; ++cc) {
        int c = threadIdx.x + cc * 256;
        float ss = reds[0][c] + reds[1][c] + reds[2][c] + reds[3][c];
        float qq = redq[0][c] + redq[1][c] + redq[2][c] + redq[3][c];
        atomicAdd(&sb[c], ss);
        atomicAdd(&sb[512 + c], qq);
    }
}

// ---------------- launch ----------------

extern "C" void kernel_launch(void* const* d_in, const int* in_sizes, int n_in,
                              void* d_out, int out_size, void* d_ws, size_t ws_size,
                              hipStream_t stream) {
    (void)in_sizes; (void)n_in; (void)out_size; (void)ws_size;
    const float* x  = (const float*)d_in[0];
    const int*   ei = (const int*)d_in[1];
    const float *W[6], *bb[5], *gg[5], *beb[5];
    for (int i = 0; i < 5; i++) {
        W[i]   = (const float*)d_in[2 + 4 * i];
        bb[i]  = (const float*)d_in[3 + 4 * i];
        gg[i]  = (const float*)d_in[4 + 4 * i];
        beb[i] = (const float*)d_in[5 + 4 * i];
    }
    W[5] = (const float*)d_in[22];
    const float* bf = (const float*)d_in[23];
    float* out = (float*)d_out;

    // workspace layout
    char* p = (char*)d_ws;
    __hip_bfloat16* hb   = (__hip_bfloat16*)p;  p += (size_t)N_PAD * D_H * 2;
    __hip_bfloat16* hagg = (__hip_bfloat16*)p;  p += (size_t)N_PAD * D_H * 2;
    __hip_bfloat16* tmpb = (__hip_bfloat16*)p;  p += (size_t)N_PAD * D_H * 2;   // row 10000 = zero row
    __hip_bfloat16* Wt0  = (__hip_bfloat16*)p;  p += (size_t)D_H * 256 * 2;
    __hip_bfloat16* Wts  = (__hip_bfloat16*)p;  p += (size_t)D_H * 512 * 2;
    float* stats  = (float*)p;  p += 5 * 8192 * 4;   // [5][8 buckets][1024]
    float* cbuf   = (float*)p;  p += 5 * 512 * 4;    // contiguous with stats for zeroing
    float* dinv   = (float*)p;  p += (N_NODES + 1) * 4;
    float* aggw   = (float*)p;  p += N_NODES * 4;
    int* counts   = (int*)p;    p += N_NODES * 4;
    int* rowptr   = (int*)p;    p += (N_NODES + 1) * 4;
    int* cursor   = (int*)p;    p += N_NODES * 4;
    int* colidx   = (int*)p;                         // <= 230000 ints (pad-8)

    // preprocessing
    k_zeroinit<<<170, 256, 0, stream>>>(stats, counts, dinv, tmpb + (size_t)N_NODES * D_H);
    k_count<<<(N_EDGES + 255) / 256, 256, 0, stream>>>(ei, dinv, counts);
    k_scan<<<1, 1024, 0, stream>>>(counts, rowptr, cursor, dinv);
    k_fill<<<(N_EDGES + 255) / 256, 256, 0, stream>>>(ei, cursor, colidx);
    k_pa<<<40, 256, 0, stream>>>(rowptr, cursor, colidx, dinv, aggw);
    k_wt<<<dim3(8, 16), 256, 0, stream>>>(W[0], Wt0, 256);
    k_xcvt<<<1250, 256, 0, stream>>>(x, hb);

    dim3 ggrid(8, N_PAD / 128);   // 632 blocks
    // layer 0
    k_gemm_mfma<1, 256><<<ggrid, 256, 0, stream>>>(hb, Wt0, dinv, nullptr, nullptr, tmpb, nullptr);
    k_agg<1, 0><<<2500, 256, 0, stream>>>(tmpb, rowptr, colidx, dinv, bb[0], nullptr, aggw,
                                          hagg, stats);
    // layers 1..4 (BN of layer l-1 folded into W[l])
    for (int l = 1; l < 5; l++) {
        k_fold<<<dim3(16, 16), 256, 0, stream>>>(W[l], gg[l - 1], beb[l - 1],
                stats + (l - 1) * 8192, Wts, cbuf + (l - 1) * 512);
        k_gemm_mfma<1, 512><<<ggrid, 256, 0, stream>>>(hagg, Wts, dinv, nullptr, nullptr, tmpb, nullptr);
        if (l < 4)
            k_agg<1, 1><<<2500, 256, 0, stream>>>(tmpb, rowptr, colidx, dinv, bb[l],
                    cbuf + (l - 1) * 512, aggw, hagg, stats + l * 8192);
        else
            k_agg<0, 1><<<2500, 256, 0, stream>>>(tmpb, rowptr, colidx, dinv, bb[l],
                    cbuf + (l - 1) * 512, aggw, hagg, stats + l * 8192);
    }
    // final: BN(layer4) folded into Wf
    k_fold<<<dim3(16, 16), 256, 0, stream>>>(W[5], gg[4], beb[4],
            stats + 4 * 8192, Wts, cbuf + 4 * 512);
    k_gemm_mfma<0, 512><<<ggrid, 256, 0, stream>>>(hagg, Wts, dinv, cbuf + 4 * 512, bf, nullptr, out);
}